// Round 2
// baseline (10792.775 us; speedup 1.0000x reference)
//
#include <hip/hip_runtime.h>

#define L_ 12
#define H_ 768
#define S_ 256
#define B_ 64
#define NH_ 12
#define HD_ 64
#define FF_ 3072
#define M_ (B_*S_)      // 16384 rows
#define QKVN (3*H_)     // 2304

using bf16x8 = __attribute__((ext_vector_type(8))) __bf16;
using floatx4 = __attribute__((ext_vector_type(4))) float;

typedef const __attribute__((address_space(1))) void* gptr_t;
typedef __attribute__((address_space(3))) void* sptr_t;

__device__ __forceinline__ void async_copy16(const void* g, void* s) {
  __builtin_amdgcn_global_load_lds((gptr_t)g, (sptr_t)s, 16, 0, 0);
}

__device__ __forceinline__ unsigned short f2bf(float f) {
  unsigned int u = __float_as_uint(f);
  u += 0x7fffu + ((u >> 16) & 1u);
  return (unsigned short)(u >> 16);
}
__device__ __forceinline__ float bflo(unsigned int u) { return __uint_as_float(u << 16); }
__device__ __forceinline__ float bfhi(unsigned int u) { return __uint_as_float(u & 0xffff0000u); }

// ---------------------------------------------------------------------------
// Weight transpose + fp32->bf16 convert: W[K,N] fp32 -> Wt[N,K] bf16
// grid = (N/64, K/64), block = 256
// ---------------------------------------------------------------------------
__global__ __launch_bounds__(256) void transpose_bf16_kernel(
    const float* __restrict__ W, unsigned short* __restrict__ Wt, int K, int N) {
  __shared__ unsigned short t[64][65];
  const int n0 = blockIdx.x * 64, k0 = blockIdx.y * 64;
  const int tid = threadIdx.x;
#pragma unroll
  for (int p = 0; p < 16; ++p) {
    int idx = p * 256 + tid;
    int r = idx >> 6, c = idx & 63;
    t[r][c] = f2bf(W[(size_t)(k0 + r) * N + n0 + c]);
  }
  __syncthreads();
#pragma unroll
  for (int p = 0; p < 16; ++p) {
    int idx = p * 256 + tid;
    int r = idx >> 6, c = idx & 63;
    Wt[(size_t)(n0 + r) * K + k0 + c] = t[c][r];
  }
}

// ---------------------------------------------------------------------------
// Concat per-layer qkv bias: out[l*2304 + j]
// ---------------------------------------------------------------------------
__global__ __launch_bounds__(256) void qkv_bias_kernel(
    const float* __restrict__ bq, const float* __restrict__ bk,
    const float* __restrict__ bv, float* __restrict__ out) {
  int i = blockIdx.x * 256 + threadIdx.x;
  if (i >= L_ * QKVN) return;
  int l = i / QKVN, j = i % QKVN;
  float v;
  if (j < H_) v = bq[l * H_ + j];
  else if (j < 2 * H_) v = bk[l * H_ + j - H_];
  else v = bv[l * H_ + j - 2 * H_];
  out[i] = v;
}

// ---------------------------------------------------------------------------
// Embedding + LayerNorm. grid = M_ (one token per block), block = 256
// ---------------------------------------------------------------------------
__global__ __launch_bounds__(256) void embed_ln_kernel(
    const int* __restrict__ ids, const int* __restrict__ tts,
    const float* __restrict__ wemb, const float* __restrict__ pemb,
    const float* __restrict__ temb, const float* __restrict__ lns,
    const float* __restrict__ lnb, float* __restrict__ h,
    unsigned short* __restrict__ hbf) {
  const int tk = blockIdx.x;
  const int s = tk & (S_ - 1);
  const int tid = threadIdx.x;
  const int id = ids[tk];
  const int tt = tts[tk];
  float v[3];
#pragma unroll
  for (int i = 0; i < 3; ++i) {
    int j = tid + i * 256;
    v[i] = wemb[(size_t)id * H_ + j] + pemb[(size_t)s * H_ + j] + temb[(size_t)tt * H_ + j];
  }
  float sum = v[0] + v[1] + v[2];
  float ssq = v[0] * v[0] + v[1] * v[1] + v[2] * v[2];
#pragma unroll
  for (int off = 32; off; off >>= 1) {
    sum += __shfl_down(sum, off);
    ssq += __shfl_down(ssq, off);
  }
  __shared__ float rs[4], rq[4];
  const int lane = tid & 63, wid = tid >> 6;
  if (lane == 0) { rs[wid] = sum; rq[wid] = ssq; }
  __syncthreads();
  const float S = rs[0] + rs[1] + rs[2] + rs[3];
  const float Q = rq[0] + rq[1] + rq[2] + rq[3];
  const float mean = S * (1.0f / 768.0f);
  const float var = Q * (1.0f / 768.0f) - mean * mean;
  const float r = rsqrtf(var + 1e-12f);
#pragma unroll
  for (int i = 0; i < 3; ++i) {
    int j = tid + i * 256;
    float y = (v[i] - mean) * r * lns[j] + lnb[j];
    h[(size_t)tk * H_ + j] = y;
    hbf[(size_t)tk * H_ + j] = f2bf(y);
  }
}

// ---------------------------------------------------------------------------
// Residual + LayerNorm: x = hin + delta; y = LN(x)*s+b -> hout (fp32) + hbf
// grid = M_, block = 256
// ---------------------------------------------------------------------------
__global__ __launch_bounds__(256) void residual_ln_kernel(
    const float* __restrict__ hin, const float* __restrict__ delta,
    const float* __restrict__ lns, const float* __restrict__ lnb,
    float* __restrict__ hout, unsigned short* __restrict__ hbf) {
  const int row = blockIdx.x;
  const int tid = threadIdx.x;
  float v[3];
#pragma unroll
  for (int i = 0; i < 3; ++i) {
    int j = tid + i * 256;
    v[i] = hin[(size_t)row * H_ + j] + delta[(size_t)row * H_ + j];
  }
  float sum = v[0] + v[1] + v[2];
  float ssq = v[0] * v[0] + v[1] * v[1] + v[2] * v[2];
#pragma unroll
  for (int off = 32; off; off >>= 1) {
    sum += __shfl_down(sum, off);
    ssq += __shfl_down(ssq, off);
  }
  __shared__ float rs[4], rq[4];
  const int lane = tid & 63, wid = tid >> 6;
  if (lane == 0) { rs[wid] = sum; rq[wid] = ssq; }
  __syncthreads();
  const float S = rs[0] + rs[1] + rs[2] + rs[3];
  const float Q = rq[0] + rq[1] + rq[2] + rq[3];
  const float mean = S * (1.0f / 768.0f);
  const float var = Q * (1.0f / 768.0f) - mean * mean;
  const float r = rsqrtf(var + 1e-12f);
#pragma unroll
  for (int i = 0; i < 3; ++i) {
    int j = tid + i * 256;
    float y = (v[i] - mean) * r * lns[j] + lnb[j];
    hout[(size_t)row * H_ + j] = y;
    hbf[(size_t)row * H_ + j] = f2bf(y);
  }
}

// ---------------------------------------------------------------------------
// GEMM: C[M,N] = A[M,K](bf16) x Bt[N,K](bf16)^T + bias[N], epilogue variants.
// block = 256 (4 waves, 2x2 of 64x64), tile 128x128, BK = 64.
// grid = (N/128, M/128)
// ---------------------------------------------------------------------------
enum { EPI_BF16 = 0, EPI_GELU = 1, EPI_F32 = 2 };

template <int EPI>
__global__ __launch_bounds__(256) void gemm_bt_kernel(
    const unsigned short* __restrict__ A, const unsigned short* __restrict__ Bt,
    const float* __restrict__ bias, void* __restrict__ Cv,
    int M, int N, int K) {
  __shared__ __align__(16) unsigned short As[128 * 64];
  __shared__ __align__(16) unsigned short Bs[128 * 64];
  const int tid = threadIdx.x;
  const int wave = tid >> 6;
  const int lane = tid & 63;
  const int m0 = blockIdx.y * 128;
  const int n0 = blockIdx.x * 128;
  const int wm = (wave & 1) * 64;
  const int wn = (wave >> 1) * 64;
  const int lr = lane & 15;
  const int quad = lane >> 4;

  floatx4 acc[4][4] = {};

  const int cid0 = wave * 256 + lane;
  for (int kt = 0; kt < K; kt += 64) {
#pragma unroll
    for (int i = 0; i < 4; ++i) {
      int cid = cid0 + i * 64;
      int row = cid >> 3, cc = cid & 7;
      async_copy16(A + (size_t)(m0 + row) * K + kt + cc * 8, &As[(wave * 4 + i) * 512]);
      async_copy16(Bt + (size_t)(n0 + row) * K + kt + cc * 8, &Bs[(wave * 4 + i) * 512]);
    }
    __syncthreads();
#pragma unroll
    for (int kk = 0; kk < 64; kk += 32) {
      bf16x8 af[4], bfr[4];
#pragma unroll
      for (int i = 0; i < 4; ++i)
        af[i] = *(const bf16x8*)&As[(wm + i * 16 + lr) * 64 + kk + quad * 8];
#pragma unroll
      for (int j = 0; j < 4; ++j)
        bfr[j] = *(const bf16x8*)&Bs[(wn + j * 16 + lr) * 64 + kk + quad * 8];
#pragma unroll
      for (int i = 0; i < 4; ++i)
#pragma unroll
        for (int j = 0; j < 4; ++j)
          acc[i][j] = __builtin_amdgcn_mfma_f32_16x16x32_bf16(af[i], bfr[j], acc[i][j], 0, 0, 0);
    }
    __syncthreads();
  }

#pragma unroll
  for (int j = 0; j < 4; ++j) {
    int n = n0 + wn + j * 16 + lr;
    float bv = bias[n];
#pragma unroll
    for (int i = 0; i < 4; ++i) {
#pragma unroll
      for (int r = 0; r < 4; ++r) {
        int m = m0 + wm + i * 16 + quad * 4 + r;
        float v = acc[i][j][r] + bv;
        if (EPI == EPI_GELU) v = 0.5f * v * (1.0f + erff(v * 0.70710678f));
        if (EPI == EPI_F32)
          ((float*)Cv)[(size_t)m * N + n] = v;
        else
          ((unsigned short*)Cv)[(size_t)m * N + n] = f2bf(v);
      }
    }
  }
}

// ---------------------------------------------------------------------------
// Attention: one (b, head) per block; online softmax, 1 query row per thread.
// qkv layout: [M, 2304] bf16, q at col h*64, k at 768+h*64, v at 1536+h*64.
// ctx out: [M, 768] bf16.  grid = B_*NH_, block = 256
// ---------------------------------------------------------------------------
__global__ __launch_bounds__(256) void attention_kernel(
    const unsigned short* __restrict__ qkv, const int* __restrict__ mask,
    unsigned short* __restrict__ ctx) {
  const int bh = blockIdx.x;
  const int b = bh / NH_, nh = bh % NH_;
  __shared__ __align__(16) unsigned short Ks[128 * 64];
  __shared__ __align__(16) unsigned short Vs[128 * 64];
  __shared__ float bias_s[256];
  const int tid = threadIdx.x;
  bias_s[tid] = (1.0f - (float)mask[b * S_ + tid]) * -10000.0f;
  const size_t rowbase = (size_t)b * S_ * QKVN;

  // load own query row -> fp32 regs
  float q[64];
  {
    const unsigned short* qp = &qkv[rowbase + (size_t)tid * QKVN + nh * 64];
#pragma unroll
    for (int c = 0; c < 8; ++c) {
      uint4 u = *(const uint4*)&qp[c * 8];
      q[c * 8 + 0] = bflo(u.x); q[c * 8 + 1] = bfhi(u.x);
      q[c * 8 + 2] = bflo(u.y); q[c * 8 + 3] = bfhi(u.y);
      q[c * 8 + 4] = bflo(u.z); q[c * 8 + 5] = bfhi(u.z);
      q[c * 8 + 6] = bflo(u.w); q[c * 8 + 7] = bfhi(u.w);
    }
  }
  float acc[64];
#pragma unroll
  for (int d = 0; d < 64; ++d) acc[d] = 0.0f;
  float mmax = -1e30f, l = 0.0f;

  for (int jt = 0; jt < S_; jt += 128) {
    __syncthreads();  // previous tile fully consumed (also covers bias_s)
#pragma unroll
    for (int p = 0; p < 4; ++p) {
      int idx = p * 256 + tid;          // 1024 chunks of 16B
      int j = idx >> 3, c = idx & 7;
      size_t g = rowbase + (size_t)(jt + j) * QKVN + nh * 64 + c * 8;
      *(uint4*)&Ks[idx * 8] = *(const uint4*)&qkv[g + H_];
      *(uint4*)&Vs[idx * 8] = *(const uint4*)&qkv[g + 2 * H_];
    }
    __syncthreads();
    for (int jj = 0; jj < 128; ++jj) {
      const unsigned short* kr = &Ks[jj * 64];
      float d0 = 0, d1 = 0, d2 = 0, d3 = 0;
#pragma unroll
      for (int c = 0; c < 8; ++c) {
        uint4 u = *(const uint4*)&kr[c * 8];
        d0 += q[c * 8 + 0] * bflo(u.x) + q[c * 8 + 1] * bfhi(u.x);
        d1 += q[c * 8 + 2] * bflo(u.y) + q[c * 8 + 3] * bfhi(u.y);
        d2 += q[c * 8 + 4] * bflo(u.z) + q[c * 8 + 5] * bfhi(u.z);
        d3 += q[c * 8 + 6] * bflo(u.w) + q[c * 8 + 7] * bfhi(u.w);
      }
      float sc = (d0 + d1 + d2 + d3) * 0.125f + bias_s[jt + jj];
      if (sc > mmax) {
        float corr = __expf(mmax - sc);
        l *= corr;
#pragma unroll
        for (int d = 0; d < 64; ++d) acc[d] *= corr;
        mmax = sc;
      }
      float p = __expf(sc - mmax);
      l += p;
      const unsigned short* vr = &Vs[jj * 64];
#pragma unroll
      for (int c = 0; c < 8; ++c) {
        uint4 u = *(const uint4*)&vr[c * 8];
        acc[c * 8 + 0] += p * bflo(u.x); acc[c * 8 + 1] += p * bfhi(u.x);
        acc[c * 8 + 2] += p * bflo(u.y); acc[c * 8 + 3] += p * bfhi(u.y);
        acc[c * 8 + 4] += p * bflo(u.z); acc[c * 8 + 5] += p * bfhi(u.z);
        acc[c * 8 + 6] += p * bflo(u.w); acc[c * 8 + 7] += p * bfhi(u.w);
      }
    }
  }
  // normalize by softmax denominator, pack to bf16, store
  const float inv = 1.0f / l;
  unsigned short* op = &ctx[((size_t)b * S_ + tid) * H_ + nh * 64];
#pragma unroll
  for (int c = 0; c < 8; ++c) {
    uint4 u;
    u.x = (unsigned)f2bf(acc[c * 8 + 0] * inv) | ((unsigned)f2bf(acc[c * 8 + 1] * inv) << 16);
    u.y = (unsigned)f2bf(acc[c * 8 + 2] * inv) | ((unsigned)f2bf(acc[c * 8 + 3] * inv) << 16);
    u.z = (unsigned)f2bf(acc[c * 8 + 4] * inv) | ((unsigned)f2bf(acc[c * 8 + 5] * inv) << 16);
    u.w = (unsigned)f2bf(acc[c * 8 + 6] * inv) | ((unsigned)f2bf(acc[c * 8 + 7] * inv) << 16);
    *(uint4*)&op[c * 8] = u;
  }
}

// ---------------------------------------------------------------------------
// Head: logits[b,l] = cls[b] . head_W[aidx[b],:,l] + head_b[aidx[b],l]
// grid = B_, block = 256
// ---------------------------------------------------------------------------
__global__ __launch_bounds__(256) void head_kernel(
    const float* __restrict__ h, const int* __restrict__ aidx,
    const float* __restrict__ hW, const float* __restrict__ hb,
    float* __restrict__ out) {
  const int b = blockIdx.x;
  const int a = aidx[b];
  const float* cls = h + (size_t)b * S_ * H_;
  const float* w = hW + (size_t)a * H_ * 2;
  float a0 = 0.f, a1 = 0.f;
  for (int j = threadIdx.x; j < H_; j += 256) {
    float c = cls[j];
    a0 += c * w[j * 2];
    a1 += c * w[j * 2 + 1];
  }
#pragma unroll
  for (int off = 32; off; off >>= 1) {
    a0 += __shfl_down(a0, off);
    a1 += __shfl_down(a1, off);
  }
  __shared__ float r0[4], r1[4];
  const int lane = threadIdx.x & 63, wid = threadIdx.x >> 6;
  if (lane == 0) { r0[wid] = a0; r1[wid] = a1; }
  __syncthreads();
  if (threadIdx.x == 0) {
    out[b * 2 + 0] = r0[0] + r0[1] + r0[2] + r0[3] + hb[a * 2 + 0];
    out[b * 2 + 1] = r1[0] + r1[1] + r1[2] + r1[3] + hb[a * 2 + 1];
  }
}

// ---------------------------------------------------------------------------
extern "C" void kernel_launch(void* const* d_in, const int* in_sizes, int n_in,
                              void* d_out, int out_size, void* d_ws, size_t ws_size,
                              hipStream_t stream) {
  const int* input_ids = (const int*)d_in[0];
  const int* attn_mask = (const int*)d_in[1];
  const int* type_ids = (const int*)d_in[2];
  const int* aidx = (const int*)d_in[3];
  const float* wemb = (const float*)d_in[4];
  const float* pemb = (const float*)d_in[5];
  const float* temb = (const float*)d_in[6];
  const float* elns = (const float*)d_in[7];
  const float* elnb = (const float*)d_in[8];
  const float* Wq = (const float*)d_in[9];
  const float* bq = (const float*)d_in[10];
  const float* Wk = (const float*)d_in[11];
  const float* bk = (const float*)d_in[12];
  const float* Wv = (const float*)d_in[13];
  const float* bv = (const float*)d_in[14];
  const float* Wo = (const float*)d_in[15];
  const float* bo = (const float*)d_in[16];
  const float* ln1s = (const float*)d_in[17];
  const float* ln1b = (const float*)d_in[18];
  const float* W1 = (const float*)d_in[19];
  const float* b1 = (const float*)d_in[20];
  const float* W2 = (const float*)d_in[21];
  const float* b2 = (const float*)d_in[22];
  const float* ln2s = (const float*)d_in[23];
  const float* ln2b = (const float*)d_in[24];
  const float* hW = (const float*)d_in[25];
  const float* hb = (const float*)d_in[26];
  float* out = (float*)d_out;
  (void)in_sizes; (void)n_in; (void)out_size; (void)ws_size;

  char* p = (char*)d_ws;
  float* h = (float*)p;              p += (size_t)M_ * H_ * 4;
  float* delta = (float*)p;          p += (size_t)M_ * H_ * 4;
  unsigned short* hbf = (unsigned short*)p;   p += (size_t)M_ * H_ * 2;
  unsigned short* qkv = (unsigned short*)p;   p += (size_t)M_ * QKVN * 2;
  unsigned short* ctx = (unsigned short*)p;   p += (size_t)M_ * H_ * 2;
  unsigned short* ffn1 = qkv;  // alias: qkv(72MB)+ctx(24MB) == 16384*3072*2
  unsigned short* wbuf = (unsigned short*)p;  p += (size_t)7077888 * 2;
  float* qkvbias = (float*)p;        p += (size_t)L_ * QKVN * 4;

  unsigned short* Wqkv_t = wbuf;                       // [2304, 768]
  unsigned short* Wo_t = wbuf + (size_t)QKVN * H_;     // [768, 768]
  unsigned short* W1_t = Wo_t + (size_t)H_ * H_;       // [3072, 768]
  unsigned short* W2_t = W1_t + (size_t)H_ * FF_;      // [768, 3072]

  qkv_bias_kernel<<<(L_ * QKVN + 255) / 256, 256, 0, stream>>>(bq, bk, bv, qkvbias);
  embed_ln_kernel<<<M_, 256, 0, stream>>>(input_ids, type_ids, wemb, pemb, temb,
                                          elns, elnb, h, hbf);

  for (int l = 0; l < L_; ++l) {
    const size_t HH = (size_t)H_ * H_;
    const size_t HF = (size_t)H_ * FF_;
    transpose_bf16_kernel<<<dim3(12, 12), 256, 0, stream>>>(Wq + l * HH, Wqkv_t, H_, H_);
    transpose_bf16_kernel<<<dim3(12, 12), 256, 0, stream>>>(Wk + l * HH, Wqkv_t + HH, H_, H_);
    transpose_bf16_kernel<<<dim3(12, 12), 256, 0, stream>>>(Wv + l * HH, Wqkv_t + 2 * HH, H_, H_);
    transpose_bf16_kernel<<<dim3(12, 12), 256, 0, stream>>>(Wo + l * HH, Wo_t, H_, H_);
    transpose_bf16_kernel<<<dim3(48, 12), 256, 0, stream>>>(W1 + l * HF, W1_t, H_, FF_);
    transpose_bf16_kernel<<<dim3(12, 48), 256, 0, stream>>>(W2 + l * HF, W2_t, FF_, H_);

    gemm_bt_kernel<EPI_BF16><<<dim3(QKVN / 128, M_ / 128), 256, 0, stream>>>(
        hbf, Wqkv_t, qkvbias + (size_t)l * QKVN, qkv, M_, QKVN, H_);
    attention_kernel<<<B_ * NH_, 256, 0, stream>>>(qkv, attn_mask, ctx);
    gemm_bt_kernel<EPI_F32><<<dim3(H_ / 128, M_ / 128), 256, 0, stream>>>(
        ctx, Wo_t, bo + (size_t)l * H_, delta, M_, H_, H_);
    residual_ln_kernel<<<M_, 256, 0, stream>>>(h, delta, ln1s + (size_t)l * H_,
                                               ln1b + (size_t)l * H_, h, hbf);
    gemm_bt_kernel<EPI_GELU><<<dim3(FF_ / 128, M_ / 128), 256, 0, stream>>>(
        hbf, W1_t, b1 + (size_t)l * FF_, ffn1, M_, FF_, H_);
    gemm_bt_kernel<EPI_F32><<<dim3(H_ / 128, M_ / 128), 256, 0, stream>>>(
        ffn1, W2_t, b2 + (size_t)l * H_, delta, M_, H_, FF_);
    residual_ln_kernel<<<M_, 256, 0, stream>>>(h, delta, ln2s + (size_t)l * H_,
                                               ln2b + (size_t)l * H_, h, hbf);
  }

  head_kernel<<<B_, 256, 0, stream>>>(h, aidx, hW, hb, out);
}

// Round 3
// 7277.244 us; speedup vs baseline: 1.4831x; 1.4831x over previous
//
#include <hip/hip_runtime.h>

#define L_ 12
#define H_ 768
#define S_ 256
#define B_ 64
#define NH_ 12
#define HD_ 64
#define FF_ 3072
#define M_ (B_*S_)      // 16384 rows
#define QKVN (3*H_)     // 2304

using bf16x8 = __attribute__((ext_vector_type(8))) __bf16;
using floatx4 = __attribute__((ext_vector_type(4))) float;

typedef const __attribute__((address_space(1))) void* gptr_t;
typedef __attribute__((address_space(3))) void* sptr_t;

__device__ __forceinline__ void async_copy16(const void* g, void* s) {
  __builtin_amdgcn_global_load_lds((gptr_t)g, (sptr_t)s, 16, 0, 0);
}

__device__ __forceinline__ unsigned short f2bf(float f) {
  unsigned int u = __float_as_uint(f);
  u += 0x7fffu + ((u >> 16) & 1u);
  return (unsigned short)(u >> 16);
}

// ---------------------------------------------------------------------------
// Weight transpose + fp32->bf16 convert: W[K,N] fp32 -> Wt[N,K] bf16
// ---------------------------------------------------------------------------
__global__ __launch_bounds__(256) void transpose_bf16_kernel(
    const float* __restrict__ W, unsigned short* __restrict__ Wt, int K, int N) {
  __shared__ unsigned short t[64][65];
  const int n0 = blockIdx.x * 64, k0 = blockIdx.y * 64;
  const int tid = threadIdx.x;
#pragma unroll
  for (int p = 0; p < 16; ++p) {
    int idx = p * 256 + tid;
    int r = idx >> 6, c = idx & 63;
    t[r][c] = f2bf(W[(size_t)(k0 + r) * N + n0 + c]);
  }
  __syncthreads();
#pragma unroll
  for (int p = 0; p < 16; ++p) {
    int idx = p * 256 + tid;
    int r = idx >> 6, c = idx & 63;
    Wt[(size_t)(n0 + r) * K + k0 + c] = t[c][r];
  }
}

// ---------------------------------------------------------------------------
// V transpose (bf16->bf16): qkv V region [s][d] -> vT[bh][d][s]
// grid = (4, 768), block = 256
// ---------------------------------------------------------------------------
__global__ __launch_bounds__(256) void v_transpose_kernel(
    const unsigned short* __restrict__ qkv, unsigned short* __restrict__ vT) {
  const int st = blockIdx.x, bh = blockIdx.y;
  const int b = bh / NH_, nh = bh % NH_;
  __shared__ unsigned short t[64][65];
  const int tid = threadIdx.x;
  const int s0 = st * 64;
  const size_t rowbase = (size_t)b * S_ * QKVN + 2 * H_ + nh * 64;
#pragma unroll
  for (int p = 0; p < 16; ++p) {
    int idx = p * 256 + tid;
    int r = idx >> 6, c = idx & 63;     // r = s-local, c = d
    t[r][c] = qkv[rowbase + (size_t)(s0 + r) * QKVN + c];
  }
  __syncthreads();
#pragma unroll
  for (int p = 0; p < 16; ++p) {
    int idx = p * 256 + tid;
    int r = idx >> 6, c = idx & 63;     // r = d, c = s-local
    vT[((size_t)bh * 64 + r) * 256 + s0 + c] = t[c][r];
  }
}

// ---------------------------------------------------------------------------
// Concat per-layer qkv bias
// ---------------------------------------------------------------------------
__global__ __launch_bounds__(256) void qkv_bias_kernel(
    const float* __restrict__ bq, const float* __restrict__ bk,
    const float* __restrict__ bv, float* __restrict__ out) {
  int i = blockIdx.x * 256 + threadIdx.x;
  if (i >= L_ * QKVN) return;
  int l = i / QKVN, j = i % QKVN;
  float v;
  if (j < H_) v = bq[l * H_ + j];
  else if (j < 2 * H_) v = bk[l * H_ + j - H_];
  else v = bv[l * H_ + j - 2 * H_];
  out[i] = v;
}

// ---------------------------------------------------------------------------
// Embedding + LayerNorm. grid = M_, block = 256
// ---------------------------------------------------------------------------
__global__ __launch_bounds__(256) void embed_ln_kernel(
    const int* __restrict__ ids, const int* __restrict__ tts,
    const float* __restrict__ wemb, const float* __restrict__ pemb,
    const float* __restrict__ temb, const float* __restrict__ lns,
    const float* __restrict__ lnb, float* __restrict__ h,
    unsigned short* __restrict__ hbf) {
  const int tk = blockIdx.x;
  const int s = tk & (S_ - 1);
  const int tid = threadIdx.x;
  const int id = ids[tk];
  const int tt = tts[tk];
  float v[3];
#pragma unroll
  for (int i = 0; i < 3; ++i) {
    int j = tid + i * 256;
    v[i] = wemb[(size_t)id * H_ + j] + pemb[(size_t)s * H_ + j] + temb[(size_t)tt * H_ + j];
  }
  float sum = v[0] + v[1] + v[2];
  float ssq = v[0] * v[0] + v[1] * v[1] + v[2] * v[2];
#pragma unroll
  for (int off = 32; off; off >>= 1) {
    sum += __shfl_down(sum, off);
    ssq += __shfl_down(ssq, off);
  }
  __shared__ float rs[4], rq[4];
  const int lane = tid & 63, wid = tid >> 6;
  if (lane == 0) { rs[wid] = sum; rq[wid] = ssq; }
  __syncthreads();
  const float S = rs[0] + rs[1] + rs[2] + rs[3];
  const float Q = rq[0] + rq[1] + rq[2] + rq[3];
  const float mean = S * (1.0f / 768.0f);
  const float var = Q * (1.0f / 768.0f) - mean * mean;
  const float r = rsqrtf(var + 1e-12f);
#pragma unroll
  for (int i = 0; i < 3; ++i) {
    int j = tid + i * 256;
    float y = (v[i] - mean) * r * lns[j] + lnb[j];
    h[(size_t)tk * H_ + j] = y;
    hbf[(size_t)tk * H_ + j] = f2bf(y);
  }
}

// ---------------------------------------------------------------------------
// Residual + LayerNorm
// ---------------------------------------------------------------------------
__global__ __launch_bounds__(256) void residual_ln_kernel(
    const float* __restrict__ hin, const float* __restrict__ delta,
    const float* __restrict__ lns, const float* __restrict__ lnb,
    float* __restrict__ hout, unsigned short* __restrict__ hbf) {
  const int row = blockIdx.x;
  const int tid = threadIdx.x;
  float v[3];
#pragma unroll
  for (int i = 0; i < 3; ++i) {
    int j = tid + i * 256;
    v[i] = hin[(size_t)row * H_ + j] + delta[(size_t)row * H_ + j];
  }
  float sum = v[0] + v[1] + v[2];
  float ssq = v[0] * v[0] + v[1] * v[1] + v[2] * v[2];
#pragma unroll
  for (int off = 32; off; off >>= 1) {
    sum += __shfl_down(sum, off);
    ssq += __shfl_down(ssq, off);
  }
  __shared__ float rs[4], rq[4];
  const int lane = tid & 63, wid = tid >> 6;
  if (lane == 0) { rs[wid] = sum; rq[wid] = ssq; }
  __syncthreads();
  const float S = rs[0] + rs[1] + rs[2] + rs[3];
  const float Q = rq[0] + rq[1] + rq[2] + rq[3];
  const float mean = S * (1.0f / 768.0f);
  const float var = Q * (1.0f / 768.0f) - mean * mean;
  const float r = rsqrtf(var + 1e-12f);
#pragma unroll
  for (int i = 0; i < 3; ++i) {
    int j = tid + i * 256;
    float y = (v[i] - mean) * r * lns[j] + lnb[j];
    hout[(size_t)row * H_ + j] = y;
    hbf[(size_t)row * H_ + j] = f2bf(y);
  }
}

// ---------------------------------------------------------------------------
// GEMM: C[M,N] = A[M,K](bf16) x Bt[N,K](bf16)^T + bias[N]
// ---------------------------------------------------------------------------
enum { EPI_BF16 = 0, EPI_GELU = 1, EPI_F32 = 2 };

template <int EPI>
__global__ __launch_bounds__(256) void gemm_bt_kernel(
    const unsigned short* __restrict__ A, const unsigned short* __restrict__ Bt,
    const float* __restrict__ bias, void* __restrict__ Cv,
    int M, int N, int K) {
  __shared__ __align__(16) unsigned short As[128 * 64];
  __shared__ __align__(16) unsigned short Bs[128 * 64];
  const int tid = threadIdx.x;
  const int wave = tid >> 6;
  const int lane = tid & 63;
  const int m0 = blockIdx.y * 128;
  const int n0 = blockIdx.x * 128;
  const int wm = (wave & 1) * 64;
  const int wn = (wave >> 1) * 64;
  const int lr = lane & 15;
  const int quad = lane >> 4;

  floatx4 acc[4][4] = {};

  const int cid0 = wave * 256 + lane;
  for (int kt = 0; kt < K; kt += 64) {
#pragma unroll
    for (int i = 0; i < 4; ++i) {
      int cid = cid0 + i * 64;
      int row = cid >> 3, cc = cid & 7;
      async_copy16(A + (size_t)(m0 + row) * K + kt + cc * 8, &As[(wave * 4 + i) * 512]);
      async_copy16(Bt + (size_t)(n0 + row) * K + kt + cc * 8, &Bs[(wave * 4 + i) * 512]);
    }
    __syncthreads();
#pragma unroll
    for (int kk = 0; kk < 64; kk += 32) {
      bf16x8 af[4], bfr[4];
#pragma unroll
      for (int i = 0; i < 4; ++i)
        af[i] = *(const bf16x8*)&As[(wm + i * 16 + lr) * 64 + kk + quad * 8];
#pragma unroll
      for (int j = 0; j < 4; ++j)
        bfr[j] = *(const bf16x8*)&Bs[(wn + j * 16 + lr) * 64 + kk + quad * 8];
#pragma unroll
      for (int i = 0; i < 4; ++i)
#pragma unroll
        for (int j = 0; j < 4; ++j)
          acc[i][j] = __builtin_amdgcn_mfma_f32_16x16x32_bf16(af[i], bfr[j], acc[i][j], 0, 0, 0);
    }
    __syncthreads();
  }

#pragma unroll
  for (int j = 0; j < 4; ++j) {
    int n = n0 + wn + j * 16 + lr;
    float bv = bias[n];
#pragma unroll
    for (int i = 0; i < 4; ++i) {
#pragma unroll
      for (int r = 0; r < 4; ++r) {
        int m = m0 + wm + i * 16 + quad * 4 + r;
        float v = acc[i][j][r] + bv;
        if (EPI == EPI_GELU) v = 0.5f * v * (1.0f + erff(v * 0.70710678f));
        if (EPI == EPI_F32)
          ((float*)Cv)[(size_t)m * N + n] = v;
        else
          ((unsigned short*)Cv)[(size_t)m * N + n] = f2bf(v);
      }
    }
  }
}

// ---------------------------------------------------------------------------
// MFMA flash attention. One (b,head) per block, 4 waves, wave owns 64 Q rows.
// KV-tile = 64. qkv: [M,2304] bf16 (q@nh*64, k@768+nh*64). vT: [bh][64][256].
// ctx out: [M,768] bf16. grid = 768, block = 256.
// ---------------------------------------------------------------------------
__global__ __launch_bounds__(256, 2) void flash_attn_kernel(
    const unsigned short* __restrict__ qkv, const unsigned short* __restrict__ vT,
    const int* __restrict__ mask, unsigned short* __restrict__ ctx) {
  const int bh = blockIdx.x;
  const int b = bh / NH_, nh = bh % NH_;
  __shared__ __align__(16) unsigned short Ks[64 * 64];    // [key][d]
  __shared__ __align__(16) unsigned short Vs[64 * 64];    // [d][key] (V^T tile)
  __shared__ __align__(16) unsigned short Ps[4][64 * 66]; // per-wave P [q][key], stride 66
  __shared__ float bias_s[256];
  const int tid = threadIdx.x;
  const int wave = tid >> 6, lane = tid & 63;
  const int lr = lane & 15, quad = lane >> 4;
  bias_s[tid] = (1.0f - (float)mask[b * S_ + tid]) * -10000.0f;

  const size_t rowbase = (size_t)b * S_ * QKVN;
  const int q0 = wave * 64;

  // Q fragments (A-layout): row = q0+i*16+lr, k = kc*32+quad*8..+7
  bf16x8 qf[4][2];
#pragma unroll
  for (int i = 0; i < 4; ++i)
#pragma unroll
    for (int kc = 0; kc < 2; ++kc)
      qf[i][kc] = *(const bf16x8*)&qkv[rowbase + (size_t)(q0 + i * 16 + lr) * QKVN +
                                       nh * 64 + kc * 32 + quad * 8];

  floatx4 o[4][4] = {};          // O: rows q (i,quad*4+r), cols d (n*16+lr)
  float mrow[4][4], lrow[4][4];  // per (i, r)
#pragma unroll
  for (int i = 0; i < 4; ++i)
#pragma unroll
    for (int r = 0; r < 4; ++r) { mrow[i][r] = -1e30f; lrow[i][r] = 0.f; }

  const size_t vbase = (size_t)bh * 64 * 256;

  for (int jt = 0; jt < S_; jt += 64) {
    __syncthreads();  // previous tile fully consumed (also covers bias_s init)
    // stage K tile [64][64] and V^T tile [64][64]: 512 x 16B chunks each
#pragma unroll
    for (int p = 0; p < 2; ++p) {
      int cid = p * 256 + wave * 64 + lane;
      int row = cid >> 3, c = cid & 7;
      async_copy16(&qkv[rowbase + (size_t)(jt + row) * QKVN + H_ + nh * 64 + c * 8],
                   &Ks[(p * 256 + wave * 64) * 8]);
      async_copy16(&vT[vbase + (size_t)row * 256 + jt + c * 8],
                   &Vs[(p * 256 + wave * 64) * 8]);
    }
    __syncthreads();

    // S = Q K^T : 4 q-tiles x 4 key-tiles, K=64 (2 MFMA)
    floatx4 s[4][4];
#pragma unroll
    for (int jn = 0; jn < 4; ++jn) {
      bf16x8 kf0 = *(const bf16x8*)&Ks[(jn * 16 + lr) * 64 + quad * 8];
      bf16x8 kf1 = *(const bf16x8*)&Ks[(jn * 16 + lr) * 64 + 32 + quad * 8];
#pragma unroll
      for (int i = 0; i < 4; ++i) {
        floatx4 a = {};
        a = __builtin_amdgcn_mfma_f32_16x16x32_bf16(qf[i][0], kf0, a, 0, 0, 0);
        a = __builtin_amdgcn_mfma_f32_16x16x32_bf16(qf[i][1], kf1, a, 0, 0, 0);
        s[i][jn] = a;
      }
    }
    // scale + mask bias (bias per key col = jt + jn*16 + lr)
    float bj[4];
#pragma unroll
    for (int jn = 0; jn < 4; ++jn) bj[jn] = bias_s[jt + jn * 16 + lr];
#pragma unroll
    for (int i = 0; i < 4; ++i)
#pragma unroll
      for (int jn = 0; jn < 4; ++jn)
#pragma unroll
        for (int r = 0; r < 4; ++r)
          s[i][jn][r] = s[i][jn][r] * 0.125f + bj[jn];

    // online softmax per row (i, quad*4+r)
#pragma unroll
    for (int i = 0; i < 4; ++i) {
#pragma unroll
      for (int r = 0; r < 4; ++r) {
        float mx = fmaxf(fmaxf(s[i][0][r], s[i][1][r]), fmaxf(s[i][2][r], s[i][3][r]));
        mx = fmaxf(mx, __shfl_xor(mx, 1));
        mx = fmaxf(mx, __shfl_xor(mx, 2));
        mx = fmaxf(mx, __shfl_xor(mx, 4));
        mx = fmaxf(mx, __shfl_xor(mx, 8));
        float mn = fmaxf(mrow[i][r], mx);
        float alpha = __expf(mrow[i][r] - mn);
        mrow[i][r] = mn;
        float ps = 0.f;
#pragma unroll
        for (int jn = 0; jn < 4; ++jn) {
          float pv = __expf(s[i][jn][r] - mn);
          s[i][jn][r] = pv;
          ps += pv;
        }
        ps += __shfl_xor(ps, 1);
        ps += __shfl_xor(ps, 2);
        ps += __shfl_xor(ps, 4);
        ps += __shfl_xor(ps, 8);
        lrow[i][r] = lrow[i][r] * alpha + ps;
#pragma unroll
        for (int n = 0; n < 4; ++n) o[i][n][r] *= alpha;
      }
    }

    // P (C-layout) -> LDS -> A-layout
#pragma unroll
    for (int i = 0; i < 4; ++i)
#pragma unroll
      for (int jn = 0; jn < 4; ++jn)
#pragma unroll
        for (int r = 0; r < 4; ++r)
          Ps[wave][(i * 16 + quad * 4 + r) * 66 + jn * 16 + lr] = f2bf(s[i][jn][r]);
    __syncthreads();  // order P writes before A-frag reads (cross-lane via LDS)

    // O += P V : A-frags from Ps, B-frags from Vs(V^T)
#pragma unroll
    for (int kc = 0; kc < 2; ++kc) {
      bf16x8 pf[4], vf[4];
#pragma unroll
      for (int i = 0; i < 4; ++i)
        pf[i] = *(const bf16x8*)&Ps[wave][(i * 16 + lr) * 66 + kc * 32 + quad * 8];
#pragma unroll
      for (int n = 0; n < 4; ++n)
        vf[n] = *(const bf16x8*)&Vs[(n * 16 + lr) * 64 + kc * 32 + quad * 8];
#pragma unroll
      for (int i = 0; i < 4; ++i)
#pragma unroll
        for (int n = 0; n < 4; ++n)
          o[i][n] = __builtin_amdgcn_mfma_f32_16x16x32_bf16(pf[i], vf[n], o[i][n], 0, 0, 0);
    }
  }

  // epilogue: normalize and store
#pragma unroll
  for (int i = 0; i < 4; ++i) {
#pragma unroll
    for (int r = 0; r < 4; ++r) {
      float inv = 1.0f / lrow[i][r];
      int row = b * S_ + q0 + i * 16 + quad * 4 + r;
#pragma unroll
      for (int n = 0; n < 4; ++n)
        ctx[(size_t)row * H_ + nh * 64 + n * 16 + lr] = f2bf(o[i][n][r] * inv);
    }
  }
}

// ---------------------------------------------------------------------------
// Head: logits[b,l] = cls[b] . head_W[aidx[b],:,l] + head_b[aidx[b],l]
// ---------------------------------------------------------------------------
__global__ __launch_bounds__(256) void head_kernel(
    const float* __restrict__ h, const int* __restrict__ aidx,
    const float* __restrict__ hW, const float* __restrict__ hb,
    float* __restrict__ out) {
  const int b = blockIdx.x;
  const int a = aidx[b];
  const float* cls = h + (size_t)b * S_ * H_;
  const float* w = hW + (size_t)a * H_ * 2;
  float a0 = 0.f, a1 = 0.f;
  for (int j = threadIdx.x; j < H_; j += 256) {
    float c = cls[j];
    a0 += c * w[j * 2];
    a1 += c * w[j * 2 + 1];
  }
#pragma unroll
  for (int off = 32; off; off >>= 1) {
    a0 += __shfl_down(a0, off);
    a1 += __shfl_down(a1, off);
  }
  __shared__ float r0[4], r1[4];
  const int lane = threadIdx.x & 63, wid = threadIdx.x >> 6;
  if (lane == 0) { r0[wid] = a0; r1[wid] = a1; }
  __syncthreads();
  if (threadIdx.x == 0) {
    out[b * 2 + 0] = r0[0] + r0[1] + r0[2] + r0[3] + hb[a * 2 + 0];
    out[b * 2 + 1] = r1[0] + r1[1] + r1[2] + r1[3] + hb[a * 2 + 1];
  }
}

// ---------------------------------------------------------------------------
extern "C" void kernel_launch(void* const* d_in, const int* in_sizes, int n_in,
                              void* d_out, int out_size, void* d_ws, size_t ws_size,
                              hipStream_t stream) {
  const int* input_ids = (const int*)d_in[0];
  const int* attn_mask = (const int*)d_in[1];
  const int* type_ids = (const int*)d_in[2];
  const int* aidx = (const int*)d_in[3];
  const float* wemb = (const float*)d_in[4];
  const float* pemb = (const float*)d_in[5];
  const float* temb = (const float*)d_in[6];
  const float* elns = (const float*)d_in[7];
  const float* elnb = (const float*)d_in[8];
  const float* Wq = (const float*)d_in[9];
  const float* bq = (const float*)d_in[10];
  const float* Wk = (const float*)d_in[11];
  const float* bk = (const float*)d_in[12];
  const float* Wv = (const float*)d_in[13];
  const float* bv = (const float*)d_in[14];
  const float* Wo = (const float*)d_in[15];
  const float* bo = (const float*)d_in[16];
  const float* ln1s = (const float*)d_in[17];
  const float* ln1b = (const float*)d_in[18];
  const float* W1 = (const float*)d_in[19];
  const float* b1 = (const float*)d_in[20];
  const float* W2 = (const float*)d_in[21];
  const float* b2 = (const float*)d_in[22];
  const float* ln2s = (const float*)d_in[23];
  const float* ln2b = (const float*)d_in[24];
  const float* hW = (const float*)d_in[25];
  const float* hb = (const float*)d_in[26];
  float* out = (float*)d_out;
  (void)in_sizes; (void)n_in; (void)out_size; (void)ws_size;

  char* p = (char*)d_ws;
  float* h = (float*)p;              p += (size_t)M_ * H_ * 4;
  float* delta = (float*)p;          p += (size_t)M_ * H_ * 4;
  unsigned short* hbf = (unsigned short*)p;   p += (size_t)M_ * H_ * 2;
  unsigned short* qkv = (unsigned short*)p;   p += (size_t)M_ * QKVN * 2;
  unsigned short* ctx = (unsigned short*)p;   p += (size_t)M_ * H_ * 2;
  unsigned short* ffn1 = qkv;  // alias: qkv(72MB)+ctx(24MB) == 16384*3072*2
  unsigned short* wbuf = (unsigned short*)p;  p += (size_t)7077888 * 2;
  float* qkvbias = (float*)p;        p += (size_t)L_ * QKVN * 4;
  // vT aliases delta: vT live only v_transpose->flash_attn; delta live only
  // attn-out GEMM->ln1 and ffn2->ln2. Disjoint. 25.2MB <= 48MB.
  unsigned short* vT = (unsigned short*)delta;

  unsigned short* Wqkv_t = wbuf;                       // [2304, 768]
  unsigned short* Wo_t = wbuf + (size_t)QKVN * H_;     // [768, 768]
  unsigned short* W1_t = Wo_t + (size_t)H_ * H_;       // [3072, 768]
  unsigned short* W2_t = W1_t + (size_t)H_ * FF_;      // [768, 3072]

  qkv_bias_kernel<<<(L_ * QKVN + 255) / 256, 256, 0, stream>>>(bq, bk, bv, qkvbias);
  embed_ln_kernel<<<M_, 256, 0, stream>>>(input_ids, type_ids, wemb, pemb, temb,
                                          elns, elnb, h, hbf);

  for (int l = 0; l < L_; ++l) {
    const size_t HH = (size_t)H_ * H_;
    const size_t HF = (size_t)H_ * FF_;
    transpose_bf16_kernel<<<dim3(12, 12), 256, 0, stream>>>(Wq + l * HH, Wqkv_t, H_, H_);
    transpose_bf16_kernel<<<dim3(12, 12), 256, 0, stream>>>(Wk + l * HH, Wqkv_t + HH, H_, H_);
    transpose_bf16_kernel<<<dim3(12, 12), 256, 0, stream>>>(Wv + l * HH, Wqkv_t + 2 * HH, H_, H_);
    transpose_bf16_kernel<<<dim3(12, 12), 256, 0, stream>>>(Wo + l * HH, Wo_t, H_, H_);
    transpose_bf16_kernel<<<dim3(48, 12), 256, 0, stream>>>(W1 + l * HF, W1_t, H_, FF_);
    transpose_bf16_kernel<<<dim3(12, 48), 256, 0, stream>>>(W2 + l * HF, W2_t, FF_, H_);

    gemm_bt_kernel<EPI_BF16><<<dim3(QKVN / 128, M_ / 128), 256, 0, stream>>>(
        hbf, Wqkv_t, qkvbias + (size_t)l * QKVN, qkv, M_, QKVN, H_);
    v_transpose_kernel<<<dim3(4, B_ * NH_), 256, 0, stream>>>(qkv, vT);
    flash_attn_kernel<<<B_ * NH_, 256, 0, stream>>>(qkv, vT, attn_mask, ctx);
    gemm_bt_kernel<EPI_F32><<<dim3(H_ / 128, M_ / 128), 256, 0, stream>>>(
        ctx, Wo_t, bo + (size_t)l * H_, delta, M_, H_, H_);
    residual_ln_kernel<<<M_, 256, 0, stream>>>(h, delta, ln1s + (size_t)l * H_,
                                               ln1b + (size_t)l * H_, h, hbf);
    gemm_bt_kernel<EPI_GELU><<<dim3(FF_ / 128, M_ / 128), 256, 0, stream>>>(
        hbf, W1_t, b1 + (size_t)l * FF_, ffn1, M_, FF_, H_);
    gemm_bt_kernel<EPI_F32><<<dim3(H_ / 128, M_ / 128), 256, 0, stream>>>(
        ffn1, W2_t, b2 + (size_t)l * H_, delta, M_, H_, FF_);
    residual_ln_kernel<<<M_, 256, 0, stream>>>(h, delta, ln2s + (size_t)l * H_,
                                               ln2b + (size_t)l * H_, h, hbf);
  }

  head_kernel<<<B_, 256, 0, stream>>>(h, aidx, hW, hb, out);
}

// Round 4
// 7149.326 us; speedup vs baseline: 1.5096x; 1.0179x over previous
//
#include <hip/hip_runtime.h>

#define L_ 12
#define H_ 768
#define S_ 256
#define B_ 64
#define NH_ 12
#define HD_ 64
#define FF_ 3072
#define M_ (B_*S_)      // 16384 rows
#define QKVN (3*H_)     // 2304

using bf16x8 = __attribute__((ext_vector_type(8))) __bf16;
using floatx4 = __attribute__((ext_vector_type(4))) float;

typedef const __attribute__((address_space(1))) void* gptr_t;
typedef __attribute__((address_space(3))) void* sptr_t;

__device__ __forceinline__ void async_copy16(const void* g, void* s) {
  __builtin_amdgcn_global_load_lds((gptr_t)g, (sptr_t)s, 16, 0, 0);
}

__device__ __forceinline__ unsigned short f2bf(float f) {
  unsigned int u = __float_as_uint(f);
  u += 0x7fffu + ((u >> 16) & 1u);
  return (unsigned short)(u >> 16);
}
__device__ __forceinline__ float bf2f(unsigned short s) {
  return __uint_as_float(((unsigned int)s) << 16);
}

// branchless tanh-form GELU: tanh(y) = 1 - 2/(1+e^{2y}) (exact at +-inf)
__device__ __forceinline__ float gelu_f(float x) {
  float y = 0.7978845608f * (x + 0.044715f * x * x * x);
  float t = 1.0f - 2.0f / (1.0f + __expf(2.0f * y));
  return 0.5f * x * (1.0f + t);
}

// ---------------------------------------------------------------------------
// Weight transpose + fp32->bf16 convert: W[K,N] fp32 -> Wt[N,K] bf16
// ---------------------------------------------------------------------------
__global__ __launch_bounds__(256) void transpose_bf16_kernel(
    const float* __restrict__ W, unsigned short* __restrict__ Wt, int K, int N) {
  __shared__ unsigned short t[64][65];
  const int n0 = blockIdx.x * 64, k0 = blockIdx.y * 64;
  const int tid = threadIdx.x;
#pragma unroll
  for (int p = 0; p < 16; ++p) {
    int idx = p * 256 + tid;
    int r = idx >> 6, c = idx & 63;
    t[r][c] = f2bf(W[(size_t)(k0 + r) * N + n0 + c]);
  }
  __syncthreads();
#pragma unroll
  for (int p = 0; p < 16; ++p) {
    int idx = p * 256 + tid;
    int r = idx >> 6, c = idx & 63;
    Wt[(size_t)(n0 + r) * K + k0 + c] = t[c][r];
  }
}

// ---------------------------------------------------------------------------
// V transpose (bf16->bf16): qkv V region [s][d] -> vT[bh][d][s]
// grid = (4, 768), block = 256
// ---------------------------------------------------------------------------
__global__ __launch_bounds__(256) void v_transpose_kernel(
    const unsigned short* __restrict__ qkv, unsigned short* __restrict__ vT) {
  const int st = blockIdx.x, bh = blockIdx.y;
  const int b = bh / NH_, nh = bh % NH_;
  __shared__ unsigned short t[64][65];
  const int tid = threadIdx.x;
  const int s0 = st * 64;
  const size_t rowbase = (size_t)b * S_ * QKVN + 2 * H_ + nh * 64;
#pragma unroll
  for (int p = 0; p < 16; ++p) {
    int idx = p * 256 + tid;
    int r = idx >> 6, c = idx & 63;     // r = s-local, c = d
    t[r][c] = qkv[rowbase + (size_t)(s0 + r) * QKVN + c];
  }
  __syncthreads();
#pragma unroll
  for (int p = 0; p < 16; ++p) {
    int idx = p * 256 + tid;
    int r = idx >> 6, c = idx & 63;     // r = d, c = s-local
    vT[((size_t)bh * 64 + r) * 256 + s0 + c] = t[c][r];
  }
}

// ---------------------------------------------------------------------------
// Concat per-layer qkv bias
// ---------------------------------------------------------------------------
__global__ __launch_bounds__(256) void qkv_bias_kernel(
    const float* __restrict__ bq, const float* __restrict__ bk,
    const float* __restrict__ bv, float* __restrict__ out) {
  int i = blockIdx.x * 256 + threadIdx.x;
  if (i >= L_ * QKVN) return;
  int l = i / QKVN, j = i % QKVN;
  float v;
  if (j < H_) v = bq[l * H_ + j];
  else if (j < 2 * H_) v = bk[l * H_ + j - H_];
  else v = bv[l * H_ + j - 2 * H_];
  out[i] = v;
}

// ---------------------------------------------------------------------------
// Embedding + LayerNorm. grid = M_, block = 256
// ---------------------------------------------------------------------------
__global__ __launch_bounds__(256) void embed_ln_kernel(
    const int* __restrict__ ids, const int* __restrict__ tts,
    const float* __restrict__ wemb, const float* __restrict__ pemb,
    const float* __restrict__ temb, const float* __restrict__ lns,
    const float* __restrict__ lnb, float* __restrict__ h,
    unsigned short* __restrict__ hbf) {
  const int tk = blockIdx.x;
  const int s = tk & (S_ - 1);
  const int tid = threadIdx.x;
  const int id = ids[tk];
  const int tt = tts[tk];
  float v[3];
#pragma unroll
  for (int i = 0; i < 3; ++i) {
    int j = tid + i * 256;
    v[i] = wemb[(size_t)id * H_ + j] + pemb[(size_t)s * H_ + j] + temb[(size_t)tt * H_ + j];
  }
  float sum = v[0] + v[1] + v[2];
  float ssq = v[0] * v[0] + v[1] * v[1] + v[2] * v[2];
#pragma unroll
  for (int off = 32; off; off >>= 1) {
    sum += __shfl_down(sum, off);
    ssq += __shfl_down(ssq, off);
  }
  __shared__ float rs[4], rq[4];
  const int lane = tid & 63, wid = tid >> 6;
  if (lane == 0) { rs[wid] = sum; rq[wid] = ssq; }
  __syncthreads();
  const float S = rs[0] + rs[1] + rs[2] + rs[3];
  const float Q = rq[0] + rq[1] + rq[2] + rq[3];
  const float mean = S * (1.0f / 768.0f);
  const float var = Q * (1.0f / 768.0f) - mean * mean;
  const float r = rsqrtf(var + 1e-12f);
#pragma unroll
  for (int i = 0; i < 3; ++i) {
    int j = tid + i * 256;
    float y = (v[i] - mean) * r * lns[j] + lnb[j];
    h[(size_t)tk * H_ + j] = y;
    hbf[(size_t)tk * H_ + j] = f2bf(y);
  }
}

// ---------------------------------------------------------------------------
// Residual + LayerNorm: x = hin + delta(bf16); y = LN(x)*s+b -> hout + hbf
// ---------------------------------------------------------------------------
__global__ __launch_bounds__(256) void residual_ln_kernel(
    const float* __restrict__ hin, const unsigned short* __restrict__ delta,
    const float* __restrict__ lns, const float* __restrict__ lnb,
    float* __restrict__ hout, unsigned short* __restrict__ hbf) {
  const int row = blockIdx.x;
  const int tid = threadIdx.x;
  float v[3];
#pragma unroll
  for (int i = 0; i < 3; ++i) {
    int j = tid + i * 256;
    v[i] = hin[(size_t)row * H_ + j] + bf2f(delta[(size_t)row * H_ + j]);
  }
  float sum = v[0] + v[1] + v[2];
  float ssq = v[0] * v[0] + v[1] * v[1] + v[2] * v[2];
#pragma unroll
  for (int off = 32; off; off >>= 1) {
    sum += __shfl_down(sum, off);
    ssq += __shfl_down(ssq, off);
  }
  __shared__ float rs[4], rq[4];
  const int lane = tid & 63, wid = tid >> 6;
  if (lane == 0) { rs[wid] = sum; rq[wid] = ssq; }
  __syncthreads();
  const float S = rs[0] + rs[1] + rs[2] + rs[3];
  const float Q = rq[0] + rq[1] + rq[2] + rq[3];
  const float mean = S * (1.0f / 768.0f);
  const float var = Q * (1.0f / 768.0f) - mean * mean;
  const float r = rsqrtf(var + 1e-12f);
#pragma unroll
  for (int i = 0; i < 3; ++i) {
    int j = tid + i * 256;
    float y = (v[i] - mean) * r * lns[j] + lnb[j];
    hout[(size_t)row * H_ + j] = y;
    hbf[(size_t)row * H_ + j] = f2bf(y);
  }
}

// ---------------------------------------------------------------------------
// GEMM: C[M,N] = A[M,K](bf16) x Bt[N,K](bf16)^T + bias[N]
// Operand-swapped MFMA: lane holds 4 consecutive N-cols -> vector stores.
// m = m0+wm+i*16+lr ; n = n0+wn+j*16+quad*4+r
// ---------------------------------------------------------------------------
enum { EPI_BF16 = 0, EPI_GELU = 1, EPI_F32 = 2 };

template <int EPI>
__global__ __launch_bounds__(256) void gemm_bt_kernel(
    const unsigned short* __restrict__ A, const unsigned short* __restrict__ Bt,
    const float* __restrict__ bias, void* __restrict__ Cv,
    int M, int N, int K) {
  __shared__ __align__(16) unsigned short As[128 * 64];
  __shared__ __align__(16) unsigned short Bs[128 * 64];
  const int tid = threadIdx.x;
  const int wave = tid >> 6;
  const int lane = tid & 63;
  const int m0 = blockIdx.y * 128;
  const int n0 = blockIdx.x * 128;
  const int wm = (wave & 1) * 64;
  const int wn = (wave >> 1) * 64;
  const int lr = lane & 15;
  const int quad = lane >> 4;

  floatx4 acc[4][4] = {};

  const int cid0 = wave * 256 + lane;
  for (int kt = 0; kt < K; kt += 64) {
#pragma unroll
    for (int i = 0; i < 4; ++i) {
      int cid = cid0 + i * 64;
      int row = cid >> 3, cc = cid & 7;
      async_copy16(A + (size_t)(m0 + row) * K + kt + cc * 8, &As[(wave * 4 + i) * 512]);
      async_copy16(Bt + (size_t)(n0 + row) * K + kt + cc * 8, &Bs[(wave * 4 + i) * 512]);
    }
    __syncthreads();
#pragma unroll
    for (int kk = 0; kk < 64; kk += 32) {
      bf16x8 af[4], bfr[4];
#pragma unroll
      for (int i = 0; i < 4; ++i)
        af[i] = *(const bf16x8*)&As[(wm + i * 16 + lr) * 64 + kk + quad * 8];
#pragma unroll
      for (int j = 0; j < 4; ++j)
        bfr[j] = *(const bf16x8*)&Bs[(wn + j * 16 + lr) * 64 + kk + quad * 8];
#pragma unroll
      for (int i = 0; i < 4; ++i)
#pragma unroll
        for (int j = 0; j < 4; ++j)
          acc[i][j] = __builtin_amdgcn_mfma_f32_16x16x32_bf16(bfr[j], af[i], acc[i][j], 0, 0, 0);
    }
    __syncthreads();
  }

#pragma unroll
  for (int j = 0; j < 4; ++j) {
    const int nb = n0 + wn + j * 16 + quad * 4;
    const float4 bv = *(const float4*)&bias[nb];
#pragma unroll
    for (int i = 0; i < 4; ++i) {
      const int m = m0 + wm + i * 16 + lr;
      float v0 = acc[i][j][0] + bv.x;
      float v1 = acc[i][j][1] + bv.y;
      float v2 = acc[i][j][2] + bv.z;
      float v3 = acc[i][j][3] + bv.w;
      if (EPI == EPI_GELU) {
        v0 = gelu_f(v0); v1 = gelu_f(v1); v2 = gelu_f(v2); v3 = gelu_f(v3);
      }
      if (EPI == EPI_F32) {
        float4 o = make_float4(v0, v1, v2, v3);
        *(float4*)&((float*)Cv)[(size_t)m * N + nb] = o;
      } else {
        uint2 o;
        o.x = (unsigned)f2bf(v0) | ((unsigned)f2bf(v1) << 16);
        o.y = (unsigned)f2bf(v2) | ((unsigned)f2bf(v3) << 16);
        *(uint2*)&((unsigned short*)Cv)[(size_t)m * N + nb] = o;
      }
    }
  }
}

// ---------------------------------------------------------------------------
// MFMA flash attention. One (b,head) per block, 4 waves, wave owns 64 Q rows.
// ---------------------------------------------------------------------------
__global__ __launch_bounds__(256, 2) void flash_attn_kernel(
    const unsigned short* __restrict__ qkv, const unsigned short* __restrict__ vT,
    const int* __restrict__ mask, unsigned short* __restrict__ ctx) {
  const int bh = blockIdx.x;
  const int b = bh / NH_, nh = bh % NH_;
  __shared__ __align__(16) unsigned short Ks[64 * 64];    // [key][d]
  __shared__ __align__(16) unsigned short Vs[64 * 64];    // [d][key] (V^T tile)
  __shared__ __align__(16) unsigned short Ps[4][64 * 66]; // per-wave P [q][key]
  __shared__ float bias_s[256];
  const int tid = threadIdx.x;
  const int wave = tid >> 6, lane = tid & 63;
  const int lr = lane & 15, quad = lane >> 4;
  bias_s[tid] = (1.0f - (float)mask[b * S_ + tid]) * -10000.0f;

  const size_t rowbase = (size_t)b * S_ * QKVN;
  const int q0 = wave * 64;

  bf16x8 qf[4][2];
#pragma unroll
  for (int i = 0; i < 4; ++i)
#pragma unroll
    for (int kc = 0; kc < 2; ++kc)
      qf[i][kc] = *(const bf16x8*)&qkv[rowbase + (size_t)(q0 + i * 16 + lr) * QKVN +
                                       nh * 64 + kc * 32 + quad * 8];

  floatx4 o[4][4] = {};
  float mrow[4][4], lrow[4][4];
#pragma unroll
  for (int i = 0; i < 4; ++i)
#pragma unroll
    for (int r = 0; r < 4; ++r) { mrow[i][r] = -1e30f; lrow[i][r] = 0.f; }

  const size_t vbase = (size_t)bh * 64 * 256;

  for (int jt = 0; jt < S_; jt += 64) {
    __syncthreads();
#pragma unroll
    for (int p = 0; p < 2; ++p) {
      int cid = p * 256 + wave * 64 + lane;
      int row = cid >> 3, c = cid & 7;
      async_copy16(&qkv[rowbase + (size_t)(jt + row) * QKVN + H_ + nh * 64 + c * 8],
                   &Ks[(p * 256 + wave * 64) * 8]);
      async_copy16(&vT[vbase + (size_t)row * 256 + jt + c * 8],
                   &Vs[(p * 256 + wave * 64) * 8]);
    }
    __syncthreads();

    floatx4 s[4][4];
#pragma unroll
    for (int jn = 0; jn < 4; ++jn) {
      bf16x8 kf0 = *(const bf16x8*)&Ks[(jn * 16 + lr) * 64 + quad * 8];
      bf16x8 kf1 = *(const bf16x8*)&Ks[(jn * 16 + lr) * 64 + 32 + quad * 8];
#pragma unroll
      for (int i = 0; i < 4; ++i) {
        floatx4 a = {};
        a = __builtin_amdgcn_mfma_f32_16x16x32_bf16(qf[i][0], kf0, a, 0, 0, 0);
        a = __builtin_amdgcn_mfma_f32_16x16x32_bf16(qf[i][1], kf1, a, 0, 0, 0);
        s[i][jn] = a;
      }
    }
    float bj[4];
#pragma unroll
    for (int jn = 0; jn < 4; ++jn) bj[jn] = bias_s[jt + jn * 16 + lr];
#pragma unroll
    for (int i = 0; i < 4; ++i)
#pragma unroll
      for (int jn = 0; jn < 4; ++jn)
#pragma unroll
        for (int r = 0; r < 4; ++r)
          s[i][jn][r] = s[i][jn][r] * 0.125f + bj[jn];

#pragma unroll
    for (int i = 0; i < 4; ++i) {
#pragma unroll
      for (int r = 0; r < 4; ++r) {
        float mx = fmaxf(fmaxf(s[i][0][r], s[i][1][r]), fmaxf(s[i][2][r], s[i][3][r]));
        mx = fmaxf(mx, __shfl_xor(mx, 1));
        mx = fmaxf(mx, __shfl_xor(mx, 2));
        mx = fmaxf(mx, __shfl_xor(mx, 4));
        mx = fmaxf(mx, __shfl_xor(mx, 8));
        float mn = fmaxf(mrow[i][r], mx);
        float alpha = __expf(mrow[i][r] - mn);
        mrow[i][r] = mn;
        float ps = 0.f;
#pragma unroll
        for (int jn = 0; jn < 4; ++jn) {
          float pv = __expf(s[i][jn][r] - mn);
          s[i][jn][r] = pv;
          ps += pv;
        }
        ps += __shfl_xor(ps, 1);
        ps += __shfl_xor(ps, 2);
        ps += __shfl_xor(ps, 4);
        ps += __shfl_xor(ps, 8);
        lrow[i][r] = lrow[i][r] * alpha + ps;
#pragma unroll
        for (int n = 0; n < 4; ++n) o[i][n][r] *= alpha;
      }
    }

#pragma unroll
    for (int i = 0; i < 4; ++i)
#pragma unroll
      for (int jn = 0; jn < 4; ++jn)
#pragma unroll
        for (int r = 0; r < 4; ++r)
          Ps[wave][(i * 16 + quad * 4 + r) * 66 + jn * 16 + lr] = f2bf(s[i][jn][r]);
    __syncthreads();

#pragma unroll
    for (int kc = 0; kc < 2; ++kc) {
      bf16x8 pf[4], vf[4];
#pragma unroll
      for (int i = 0; i < 4; ++i)
        pf[i] = *(const bf16x8*)&Ps[wave][(i * 16 + lr) * 66 + kc * 32 + quad * 8];
#pragma unroll
      for (int n = 0; n < 4; ++n)
        vf[n] = *(const bf16x8*)&Vs[(n * 16 + lr) * 64 + kc * 32 + quad * 8];
#pragma unroll
      for (int i = 0; i < 4; ++i)
#pragma unroll
        for (int n = 0; n < 4; ++n)
          o[i][n] = __builtin_amdgcn_mfma_f32_16x16x32_bf16(pf[i], vf[n], o[i][n], 0, 0, 0);
    }
  }

#pragma unroll
  for (int i = 0; i < 4; ++i) {
#pragma unroll
    for (int r = 0; r < 4; ++r) {
      float inv = 1.0f / lrow[i][r];
      int row = b * S_ + q0 + i * 16 + quad * 4 + r;
#pragma unroll
      for (int n = 0; n < 4; ++n)
        ctx[(size_t)row * H_ + nh * 64 + n * 16 + lr] = f2bf(o[i][n][r] * inv);
    }
  }
}

// ---------------------------------------------------------------------------
// Head
// ---------------------------------------------------------------------------
__global__ __launch_bounds__(256) void head_kernel(
    const float* __restrict__ h, const int* __restrict__ aidx,
    const float* __restrict__ hW, const float* __restrict__ hb,
    float* __restrict__ out) {
  const int b = blockIdx.x;
  const int a = aidx[b];
  const float* cls = h + (size_t)b * S_ * H_;
  const float* w = hW + (size_t)a * H_ * 2;
  float a0 = 0.f, a1 = 0.f;
  for (int j = threadIdx.x; j < H_; j += 256) {
    float c = cls[j];
    a0 += c * w[j * 2];
    a1 += c * w[j * 2 + 1];
  }
#pragma unroll
  for (int off = 32; off; off >>= 1) {
    a0 += __shfl_down(a0, off);
    a1 += __shfl_down(a1, off);
  }
  __shared__ float r0[4], r1[4];
  const int lane = threadIdx.x & 63, wid = threadIdx.x >> 6;
  if (lane == 0) { r0[wid] = a0; r1[wid] = a1; }
  __syncthreads();
  if (threadIdx.x == 0) {
    out[b * 2 + 0] = r0[0] + r0[1] + r0[2] + r0[3] + hb[a * 2 + 0];
    out[b * 2 + 1] = r1[0] + r1[1] + r1[2] + r1[3] + hb[a * 2 + 1];
  }
}

// ---------------------------------------------------------------------------
extern "C" void kernel_launch(void* const* d_in, const int* in_sizes, int n_in,
                              void* d_out, int out_size, void* d_ws, size_t ws_size,
                              hipStream_t stream) {
  const int* input_ids = (const int*)d_in[0];
  const int* attn_mask = (const int*)d_in[1];
  const int* type_ids = (const int*)d_in[2];
  const int* aidx = (const int*)d_in[3];
  const float* wemb = (const float*)d_in[4];
  const float* pemb = (const float*)d_in[5];
  const float* temb = (const float*)d_in[6];
  const float* elns = (const float*)d_in[7];
  const float* elnb = (const float*)d_in[8];
  const float* Wq = (const float*)d_in[9];
  const float* bq = (const float*)d_in[10];
  const float* Wk = (const float*)d_in[11];
  const float* bk = (const float*)d_in[12];
  const float* Wv = (const float*)d_in[13];
  const float* bv = (const float*)d_in[14];
  const float* Wo = (const float*)d_in[15];
  const float* bo = (const float*)d_in[16];
  const float* ln1s = (const float*)d_in[17];
  const float* ln1b = (const float*)d_in[18];
  const float* W1 = (const float*)d_in[19];
  const float* b1 = (const float*)d_in[20];
  const float* W2 = (const float*)d_in[21];
  const float* b2 = (const float*)d_in[22];
  const float* ln2s = (const float*)d_in[23];
  const float* ln2b = (const float*)d_in[24];
  const float* hW = (const float*)d_in[25];
  const float* hb = (const float*)d_in[26];
  float* out = (float*)d_out;
  (void)in_sizes; (void)n_in; (void)out_size; (void)ws_size;

  char* p = (char*)d_ws;
  float* h = (float*)p;              p += (size_t)M_ * H_ * 4;
  unsigned short* delta = (unsigned short*)p;  p += (size_t)M_ * H_ * 4; // bf16, slot kept fp32-sized
  unsigned short* hbf = (unsigned short*)p;   p += (size_t)M_ * H_ * 2;
  unsigned short* qkv = (unsigned short*)p;   p += (size_t)M_ * QKVN * 2;
  unsigned short* ctx = (unsigned short*)p;   p += (size_t)M_ * H_ * 2;
  unsigned short* ffn1 = qkv;  // alias: qkv(72MB)+ctx(24MB) == 16384*3072*2
  unsigned short* wbuf = (unsigned short*)p;  p += (size_t)7077888 * 2;
  float* qkvbias = (float*)p;        p += (size_t)L_ * QKVN * 4;
  // vT aliases delta slot: vT live v_transpose->flash_attn; delta live
  // attn-out GEMM->ln1 / ffn2->ln2. Disjoint lifetimes.
  unsigned short* vT = delta;

  unsigned short* Wqkv_t = wbuf;                       // [2304, 768]
  unsigned short* Wo_t = wbuf + (size_t)QKVN * H_;     // [768, 768]
  unsigned short* W1_t = Wo_t + (size_t)H_ * H_;       // [3072, 768]
  unsigned short* W2_t = W1_t + (size_t)H_ * FF_;      // [768, 3072]

  qkv_bias_kernel<<<(L_ * QKVN + 255) / 256, 256, 0, stream>>>(bq, bk, bv, qkvbias);
  embed_ln_kernel<<<M_, 256, 0, stream>>>(input_ids, type_ids, wemb, pemb, temb,
                                          elns, elnb, h, hbf);

  for (int l = 0; l < L_; ++l) {
    const size_t HH = (size_t)H_ * H_;
    const size_t HF = (size_t)H_ * FF_;
    transpose_bf16_kernel<<<dim3(12, 12), 256, 0, stream>>>(Wq + l * HH, Wqkv_t, H_, H_);
    transpose_bf16_kernel<<<dim3(12, 12), 256, 0, stream>>>(Wk + l * HH, Wqkv_t + HH, H_, H_);
    transpose_bf16_kernel<<<dim3(12, 12), 256, 0, stream>>>(Wv + l * HH, Wqkv_t + 2 * HH, H_, H_);
    transpose_bf16_kernel<<<dim3(12, 12), 256, 0, stream>>>(Wo + l * HH, Wo_t, H_, H_);
    transpose_bf16_kernel<<<dim3(48, 12), 256, 0, stream>>>(W1 + l * HF, W1_t, H_, FF_);
    transpose_bf16_kernel<<<dim3(12, 48), 256, 0, stream>>>(W2 + l * HF, W2_t, FF_, H_);

    gemm_bt_kernel<EPI_BF16><<<dim3(QKVN / 128, M_ / 128), 256, 0, stream>>>(
        hbf, Wqkv_t, qkvbias + (size_t)l * QKVN, qkv, M_, QKVN, H_);
    v_transpose_kernel<<<dim3(4, B_ * NH_), 256, 0, stream>>>(qkv, vT);
    flash_attn_kernel<<<B_ * NH_, 256, 0, stream>>>(qkv, vT, attn_mask, ctx);
    gemm_bt_kernel<EPI_BF16><<<dim3(H_ / 128, M_ / 128), 256, 0, stream>>>(
        ctx, Wo_t, bo + (size_t)l * H_, delta, M_, H_, H_);
    residual_ln_kernel<<<M_, 256, 0, stream>>>(h, delta, ln1s + (size_t)l * H_,
                                               ln1b + (size_t)l * H_, h, hbf);
    gemm_bt_kernel<EPI_GELU><<<dim3(FF_ / 128, M_ / 128), 256, 0, stream>>>(
        hbf, W1_t, b1 + (size_t)l * FF_, ffn1, M_, FF_, H_);
    gemm_bt_kernel<EPI_BF16><<<dim3(H_ / 128, M_ / 128), 256, 0, stream>>>(
        ffn1, W2_t, b2 + (size_t)l * H_, delta, M_, H_, FF_);
    residual_ln_kernel<<<M_, 256, 0, stream>>>(h, delta, ln2s + (size_t)l * H_,
                                               ln2b + (size_t)l * H_, h, hbf);
  }

  head_kernel<<<B_, 256, 0, stream>>>(h, aidx, hW, hb, out);
}